// Round 7
// baseline (689.944 us; speedup 1.0000x reference)
//
#include <hip/hip_runtime.h>

#define NN 16384
#define NCB 8
#define DIM 32
#define CB 1024
#define RPB 512          // rows per block (one k)
#define QC 256           // codebook entries per wave (quarter)
#define TILE 64          // entries per LDS tile
#define NT (QC / TILE)   // 4 tiles per wave

// Kernel A: csqb[k*CB+c] = ||codebook[k,c]||^2 + rate_bias[k,c]
__global__ __launch_bounds__(256) void vq_csq(const float* __restrict__ cb,
                                              const float* __restrict__ rb,
                                              float* __restrict__ out) {
    int i = blockIdx.x * 256 + threadIdx.x;
    if (i >= NCB * CB) return;
    const float4* c4 = reinterpret_cast<const float4*>(cb + (size_t)i * DIM);
    float s0 = 0.f, s1 = 0.f, s2 = 0.f, s3 = 0.f;
#pragma unroll
    for (int j = 0; j < 8; ++j) {
        float4 v = c4[j];
        s0 = fmaf(v.x, v.x, s0);
        s1 = fmaf(v.y, v.y, s1);
        s2 = fmaf(v.z, v.z, s2);
        s3 = fmaf(v.w, v.w, s3);
    }
    out[i] = ((s0 + s1) + (s2 + s3)) + rb[i];
}

// Fused kernel: 256 blocks (1/CU, pinned by 81 KB LDS) x 256 threads.
// Block = one k, 512 rows. Wave w scans quarter [w*256, w*256+256) of the
// codebook for ALL 512 rows (8 rows/thread), from per-wave private
// double-buffered LDS tiles (broadcast ds_read_b128; ~96 LDS cyc feeding
// ~680 VALU cyc per entry -> VALU/store-bound, not LDS-bound). one_hot
// zero-stores are interleaved 2/c; steady-state issue (~12 B/cyc/CU) matches
// the HBM drain rate so vmcnt waits stay short and no barrier ever drains
// them. Quarters combine via LDS partials + ONE __syncthreads (which also
// orders all zeros before the 1.0 scatter). Quarter indices ascend with w,
// so strict < reduction preserves argmin first-occurrence. Distance chain
// is bit-frozen to rounds 2-6.
__global__ __launch_bounds__(256, 1) void vq_fused(
    const float* __restrict__ x, const float* __restrict__ cb,
    const float* __restrict__ csqb, float* __restrict__ xhat,
    float* __restrict__ onehot, float* __restrict__ idxf) {
    __shared__ float4 tiles[4][2][TILE * 8];  // 64 KB: 4 waves x dbuf x 8 KB
    __shared__ float pd[4][RPB + 32];         // +32 pad: LDS >80KB => 1 blk/CU
    __shared__ int pi[4][RPB + 32];

    const int tid = threadIdx.x;
    const int w = tid >> 6;    // wave id = codebook quarter
    const int lane = tid & 63;
    const int k = blockIdx.x & (NCB - 1);
    const int n0 = (blockIdx.x >> 3) * RPB;

    const float4* cbk4 =
        reinterpret_cast<const float4*>(cb + (size_t)k * CB * DIM);
    const float* cqk = csqb + (size_t)k * CB;

    // ---- x rows -> registers (lane owns rows n0+lane*8 .. +7); ||x||^2 ----
    float4 xr[8][8];
    float xsq[8];
#pragma unroll
    for (int j = 0; j < 8; ++j) {
        const int n = n0 + lane * 8 + j;
        const float4* xp =
            reinterpret_cast<const float4*>(x + ((size_t)n * NCB + k) * DIM);
#pragma unroll
        for (int jj = 0; jj < 8; ++jj) xr[j][jj] = xp[jj];
        float q0 = 0.f, q1 = 0.f, q2 = 0.f, q3 = 0.f;
#pragma unroll
        for (int jj = 0; jj < 8; ++jj) {
            q0 = fmaf(xr[j][jj].x, xr[j][jj].x, q0);
            q1 = fmaf(xr[j][jj].y, xr[j][jj].y, q1);
            q2 = fmaf(xr[j][jj].z, xr[j][jj].z, q2);
            q3 = fmaf(xr[j][jj].w, xr[j][jj].w, q3);
        }
        xsq[j] = (q0 + q1) + (q2 + q3);
    }

    float best[8];
    int bi[8];
#pragma unroll
    for (int j = 0; j < 8; ++j) {
        best[j] = 3.4028235e38f;
        bi[j] = 0;
    }

    // ---- prologue: stage tile 0 of this wave's quarter ----
    const int qbase = w * QC;
    float4 st[8];
    float cq_cur, cq_nxt = 0.f;
#pragma unroll
    for (int i = 0; i < 8; ++i) st[i] = cbk4[(size_t)qbase * 8 + i * 64 + lane];
    cq_cur = cqk[qbase + lane];
#pragma unroll
    for (int i = 0; i < 8; ++i) tiles[w][0][i * 64 + lane] = st[i];

    float4* oh4 = reinterpret_cast<float4*>(onehot);
    const float4 z4 = make_float4(0.f, 0.f, 0.f, 0.f);

    for (int t = 0; t < NT; ++t) {
        const int b = t & 1;
        // prefetch next tile into registers (loads enter FIFO before this
        // phase's stores; steady-state store queue is short so the
        // pre-ds_write vmcnt wait is cheap)
        if (t < NT - 1) {
#pragma unroll
            for (int i = 0; i < 8; ++i)
                st[i] = cbk4[((size_t)qbase + (t + 1) * TILE) * 8 + i * 64 +
                             lane];
            cq_nxt = cqk[qbase + (t + 1) * TILE + lane];
        }

        const float4* buf = &tiles[w][b][0];
#pragma unroll 2
        for (int c = 0; c < TILE; ++c) {
            // interleaved zero-fill: half a one_hot row (2 KB) per c.
            // wave w owns rows [w*128, w*128+128) across its 4 phases.
            {
                const int zrow = n0 + w * 128 + t * 32 + (c >> 1);
                float4* rp = oh4 + ((size_t)zrow * NCB + k) * 256;
                rp[(c & 1) * 128 + lane] = z4;
                rp[(c & 1) * 128 + 64 + lane] = z4;
            }

            const float cqv = __int_as_float(
                __builtin_amdgcn_readlane(__float_as_int(cq_cur), c));
            float4 A[8];
#pragma unroll
            for (int jj = 0; jj < 8; ++jj) A[jj] = buf[c * 8 + jj];
            const int cg = qbase + t * TILE + c;

#pragma unroll
            for (int j = 0; j < 8; ++j) {
                // frozen round-2 chain order
                float d0 = 0.f, d1 = 0.f, d2 = 0.f, d3 = 0.f;
#pragma unroll
                for (int jj = 0; jj < 8; ++jj) {
                    d0 = fmaf(xr[j][jj].x, A[jj].x, d0);
                    d1 = fmaf(xr[j][jj].y, A[jj].y, d1);
                    d2 = fmaf(xr[j][jj].z, A[jj].z, d2);
                    d3 = fmaf(xr[j][jj].w, A[jj].w, d3);
                }
                const float dot = (d0 + d1) + (d2 + d3);
                const float dist = fmaf(-2.f, dot, xsq[j] + cqv);
                if (dist < best[j]) {  // strict <: first occurrence in quarter
                    best[j] = dist;
                    bi[j] = cg;
                }
            }
        }

        if (t < NT - 1) {
#pragma unroll
            for (int i = 0; i < 8; ++i) tiles[w][b ^ 1][i * 64 + lane] = st[i];
            cq_cur = cq_nxt;
        }
    }

    // ---- publish this wave's per-row partials ----
#pragma unroll
    for (int j = 0; j < 8; ++j) {
        pd[w][lane * 8 + j] = best[j];
        pi[w][lane * 8 + j] = bi[j];
    }
    __syncthreads();  // partials visible + ALL zero-stores drained (vmcnt 0)

    // ---- combine quarters + scatter; wave w handles rows [w*128,+128) ----
#pragma unroll
    for (int e = 0; e < 2; ++e) {
        const int r = w * 128 + lane * 2 + e;
        float bd = pd[0][r];
        int bx = pi[0][r];
#pragma unroll
        for (int q = 1; q < 4; ++q) {
            const float dq = pd[q][r];
            const int iq = pi[q][r];
            // ascending quarters => on tie keep lower (earlier) index
            if (dq < bd) {
                bd = dq;
                bx = iq;
            }
        }
        const int n = n0 + r;
        idxf[(size_t)n * NCB + k] = (float)bx;
        const float4* src = cbk4 + (size_t)bx * 8;
        float4* dst =
            reinterpret_cast<float4*>(xhat + ((size_t)n * NCB + k) * DIM);
#pragma unroll
        for (int jj = 0; jj < 8; ++jj) dst[jj] = src[jj];
        onehot[((size_t)n * NCB + k) * CB + bx] = 1.0f;
    }
}

extern "C" void kernel_launch(void* const* d_in, const int* in_sizes, int n_in,
                              void* d_out, int out_size, void* d_ws,
                              size_t ws_size, hipStream_t stream) {
    const float* x = (const float*)d_in[0];
    const float* cb = (const float*)d_in[1];
    const float* rb = (const float*)d_in[2];

    float* out = (float*)d_out;
    float* xhat = out;                             // N*NCB*DIM
    float* onehot = out + (size_t)NN * NCB * DIM;  // N*NCB*CB
    float* idxf = onehot + (size_t)NN * NCB * CB;  // N*NCB

    float* csqb = (float*)d_ws;  // NCB*CB floats = 32 KB

    vq_csq<<<(NCB * CB + 255) / 256, 256, 0, stream>>>(cb, rb, csqb);
    vq_fused<<<(NN / RPB) * NCB, 256, 0, stream>>>(x, cb, csqb, xhat, onehot,
                                                   idxf);
}

// Round 8
// 178.191 us; speedup vs baseline: 3.8719x; 3.8719x over previous
//
#include <hip/hip_runtime.h>

#define NN 16384
#define NCB 8
#define DIM 32
#define CB 1024
#define RPB 512         // rows per block (one k)
#define QC 256          // codebook entries per wave (quarter)
#define TILE 64         // entries per LDS tile
#define NT (QC / TILE)  // 4 tiles per wave

// Kernel A: csqb[k*CB+c] = ||codebook[k,c]||^2 + rate_bias[k,c]
__global__ __launch_bounds__(256) void vq_csq(const float* __restrict__ cb,
                                              const float* __restrict__ rb,
                                              float* __restrict__ out) {
    int i = blockIdx.x * 256 + threadIdx.x;
    if (i >= NCB * CB) return;
    const float4* c4 = reinterpret_cast<const float4*>(cb + (size_t)i * DIM);
    float s0 = 0.f, s1 = 0.f, s2 = 0.f, s3 = 0.f;
#pragma unroll
    for (int j = 0; j < 8; ++j) {
        float4 v = c4[j];
        s0 = fmaf(v.x, v.x, s0);
        s1 = fmaf(v.y, v.y, s1);
        s2 = fmaf(v.z, v.z, s2);
        s3 = fmaf(v.w, v.w, s3);
    }
    out[i] = ((s0 + s1) + (s2 + s3)) + rb[i];
}

// Fused kernel: 256 blocks (1/CU, LDS-pinned) x 512 threads (8 waves,
// 2/SIMD). Block = one k, 512 rows. Wave w = (rh = w>>2, q = w&3): scans
// codebook quarter [q*256, q*256+256) for rows [rh*256, rh*256+256)
// (4 rows/thread -> ~225 VGPR, NO spill; round 7's R=8 needed 256+ and
// spilled). Each entry is ds_read by only 2 waves (one per row half):
// 16384 b128/CU ~= 82 us, balanced against ~72 us VALU and ~84 us one_hot
// store drain. Zero-stores interleaved 1/c drain in background (no barrier
// in the loop); ONE __syncthreads orders them before the 1.0 scatter and
// publishes partials. Quarters ascend with q + strict < => exact
// first-occurrence argmin. Distance chain bit-frozen to rounds 2-7.
__global__ __launch_bounds__(512, 2) void vq_fused(
    const float* __restrict__ x, const float* __restrict__ cb,
    const float* __restrict__ csqb, float* __restrict__ xhat,
    float* __restrict__ onehot, float* __restrict__ idxf) {
    __shared__ float4 tiles[8][2][TILE * 8];  // 128 KB
    __shared__ float pd[4][RPB];              // 8 KB
    __shared__ int pi[4][RPB];                // 8 KB -> 144 KB total: 1 blk/CU

    const int tid = threadIdx.x;
    const int w = tid >> 6;
    const int lane = tid & 63;
    const int rh = w >> 2;  // row half
    const int q = w & 3;    // codebook quarter
    const int k = blockIdx.x & (NCB - 1);
    const int n0 = (blockIdx.x >> 3) * RPB;

    const float4* cbk4 =
        reinterpret_cast<const float4*>(cb + (size_t)k * CB * DIM);
    const float* cqk = csqb + (size_t)k * CB;

    // ---- 4 x-rows -> registers; ||x||^2 (frozen chain) ----
    const int rbase = rh * 256 + lane * 4;  // block-local row of xr[0]
    float4 xr[4][8];
    float xsq[4];
#pragma unroll
    for (int j = 0; j < 4; ++j) {
        const int n = n0 + rbase + j;
        const float4* xp =
            reinterpret_cast<const float4*>(x + ((size_t)n * NCB + k) * DIM);
#pragma unroll
        for (int jj = 0; jj < 8; ++jj) xr[j][jj] = xp[jj];
        float q0 = 0.f, q1 = 0.f, q2 = 0.f, q3 = 0.f;
#pragma unroll
        for (int jj = 0; jj < 8; ++jj) {
            q0 = fmaf(xr[j][jj].x, xr[j][jj].x, q0);
            q1 = fmaf(xr[j][jj].y, xr[j][jj].y, q1);
            q2 = fmaf(xr[j][jj].z, xr[j][jj].z, q2);
            q3 = fmaf(xr[j][jj].w, xr[j][jj].w, q3);
        }
        xsq[j] = (q0 + q1) + (q2 + q3);
    }

    float best[4];
    int bi[4];
#pragma unroll
    for (int j = 0; j < 4; ++j) {
        best[j] = 3.4028235e38f;
        bi[j] = 0;
    }

    // ---- prologue: stage tile 0 of this wave's quarter ----
    const int qbase = q * QC;
    float4 st[8];
    float cq_cur, cq_nxt = 0.f;
#pragma unroll
    for (int i = 0; i < 8; ++i) st[i] = cbk4[(size_t)qbase * 8 + i * 64 + lane];
    cq_cur = cqk[qbase + lane];
#pragma unroll
    for (int i = 0; i < 8; ++i) tiles[w][0][i * 64 + lane] = st[i];

    float4* oh4 = reinterpret_cast<float4*>(onehot);
    const float4 z4 = make_float4(0.f, 0.f, 0.f, 0.f);

    for (int t = 0; t < NT; ++t) {
        const int b = t & 1;
        // prefetch next tile into regs (loads are OLDEST in the vmcnt FIFO,
        // so the pre-ds_write wait never has to drain this phase's stores)
        if (t < NT - 1) {
#pragma unroll
            for (int i = 0; i < 8; ++i)
                st[i] = cbk4[((size_t)qbase + (t + 1) * TILE) * 8 + i * 64 +
                             lane];
            cq_nxt = cqk[qbase + (t + 1) * TILE + lane];
        }

        const float4* buf = &tiles[w][b][0];
#pragma unroll 2
        for (int c = 0; c < TILE; ++c) {
            // interleaved zero-fill: 1 KB per c; wave w owns 64 rows.
            {
                const int zrow = n0 + w * 64 + t * 16 + (c >> 2);
                float4* rp = oh4 + ((size_t)zrow * NCB + k) * 256;
                rp[(c & 3) * 64 + lane] = z4;
            }

            const float cqv = __int_as_float(
                __builtin_amdgcn_readlane(__float_as_int(cq_cur), c));
            float4 A[8];
#pragma unroll
            for (int jj = 0; jj < 8; ++jj) A[jj] = buf[c * 8 + jj];
            const int cg = qbase + t * TILE + c;

#pragma unroll
            for (int j = 0; j < 4; ++j) {
                // frozen round-2 chain order
                float d0 = 0.f, d1 = 0.f, d2 = 0.f, d3 = 0.f;
#pragma unroll
                for (int jj = 0; jj < 8; ++jj) {
                    d0 = fmaf(xr[j][jj].x, A[jj].x, d0);
                    d1 = fmaf(xr[j][jj].y, A[jj].y, d1);
                    d2 = fmaf(xr[j][jj].z, A[jj].z, d2);
                    d3 = fmaf(xr[j][jj].w, A[jj].w, d3);
                }
                const float dot = (d0 + d1) + (d2 + d3);
                const float dist = fmaf(-2.f, dot, xsq[j] + cqv);
                if (dist < best[j]) {  // strict <: first occurrence in quarter
                    best[j] = dist;
                    bi[j] = cg;
                }
            }
        }

        if (t < NT - 1) {
#pragma unroll
            for (int i = 0; i < 8; ++i) tiles[w][b ^ 1][i * 64 + lane] = st[i];
            cq_cur = cq_nxt;
        }
    }

    // ---- publish per-quarter partials ----
#pragma unroll
    for (int j = 0; j < 4; ++j) {
        pd[q][rbase + j] = best[j];
        pi[q][rbase + j] = bi[j];
    }
    __syncthreads();  // partials visible + ALL zero-stores drained (vmcnt 0)

    // ---- combine quarters + scatter; thread tid owns block-row tid ----
    {
        const int r = tid;
        float bd = pd[0][r];
        int bx = pi[0][r];
#pragma unroll
        for (int qq = 1; qq < 4; ++qq) {
            const float dq = pd[qq][r];
            const int iq = pi[qq][r];
            // ascending quarters => on tie keep lower (earlier) index
            if (dq < bd) {
                bd = dq;
                bx = iq;
            }
        }
        const int n = n0 + r;
        idxf[(size_t)n * NCB + k] = (float)bx;
        const float4* src = cbk4 + (size_t)bx * 8;
        float4* dst =
            reinterpret_cast<float4*>(xhat + ((size_t)n * NCB + k) * DIM);
#pragma unroll
        for (int jj = 0; jj < 8; ++jj) dst[jj] = src[jj];
        onehot[((size_t)n * NCB + k) * CB + bx] = 1.0f;
    }
}

extern "C" void kernel_launch(void* const* d_in, const int* in_sizes, int n_in,
                              void* d_out, int out_size, void* d_ws,
                              size_t ws_size, hipStream_t stream) {
    const float* x = (const float*)d_in[0];
    const float* cb = (const float*)d_in[1];
    const float* rb = (const float*)d_in[2];

    float* out = (float*)d_out;
    float* xhat = out;                             // N*NCB*DIM
    float* onehot = out + (size_t)NN * NCB * DIM;  // N*NCB*CB
    float* idxf = onehot + (size_t)NN * NCB * CB;  // N*NCB

    float* csqb = (float*)d_ws;  // NCB*CB floats = 32 KB

    vq_csq<<<(NCB * CB + 255) / 256, 256, 0, stream>>>(cb, rb, csqb);
    vq_fused<<<(NN / RPB) * NCB, 512, 0, stream>>>(x, cb, csqb, xhat, onehot,
                                                   idxf);
}